// Round 8
// baseline (408.296 us; speedup 1.0000x reference)
//
#include <hip/hip_runtime.h>
#include <cstdint>
#include <cstddef>

constexpr int NN = 50000;
constexpr int NE = 800000;

typedef short bf16x8 __attribute__((ext_vector_type(8)));
typedef short short4v __attribute__((ext_vector_type(4)));
typedef float f32x16 __attribute__((ext_vector_type(16)));
typedef _Float16 half4v __attribute__((ext_vector_type(4)));
typedef unsigned short ushort_t;

__device__ inline unsigned short f2bf(float f) {
  unsigned u = __float_as_uint(f);
  return (unsigned short)((u + 0x7FFFu + ((u >> 16) & 1u)) >> 16);
}
__device__ inline float bf2f(unsigned short h) {
  return __uint_as_float(((unsigned)h) << 16);
}
__device__ inline ushort_t f2h(float f) {
  _Float16 h = (_Float16)f;
  return __builtin_bit_cast(ushort_t, h);
}

// ---- pre-transform weights W[M][K] fp32 -> frag-order bf16 hi/lo (B operand) -
// idx = ((cb*(K/16)+kb)*64 + l)*8 + j ; col = cb*32+(l&31); k = kb*16+((l>>5)&1)*8+j
__global__ void k_wconv(const float* __restrict__ W, short* __restrict__ Bh,
                        short* __restrict__ Bl, int M, int K, int total) {
  int idx = blockIdx.x * 256 + threadIdx.x;
  if (idx >= total) return;
  int j = idx & 7;
  int l = (idx >> 3) & 63;
  int blk = idx >> 9;
  int nKB = K >> 4;
  int cb = blk / nKB, kb = blk - cb * nKB;
  int col = cb * 32 + (l & 31);
  int k = kb * 16 + ((l >> 5) & 1) * 8 + j;
  float v = (col < M) ? W[(size_t)col * K + k] : 0.f;
  unsigned short h = f2bf(v);
  Bh[idx] = (short)h;
  Bl[idx] = (short)f2bf(v - bf2f(h));
}

// ---- shared epilogue: OUTMODE 0=f32, 1=f16, 2=A-frag-order bf16 hi/lo --------
template<int ACT, int OUTMODE>
__device__ inline void epi_store(const f32x16& acc, int row0w, int cc, int lane,
    float bv, float* __restrict__ C, ushort_t* __restrict__ C16,
    short* __restrict__ Fh, short* __restrict__ Fl, int N, int M, int nKBo)
{
  #pragma unroll
  for (int r = 0; r < 16; ++r) {
    int rr = row0w + (r & 3) + 8 * (r >> 2) + 4 * (lane >> 5);
    if (rr >= N || cc >= M) continue;
    float v = acc[r] + bv;
    if (ACT) v = v > 0.f ? v : (__expf(v) - 1.f);
    if (OUTMODE == 0) {
      C[(size_t)rr * M + cc] = v;
    } else if (OUTMODE == 1) {
      C16[(size_t)rr * M + cc] = f2h(v);
    } else {
      unsigned short h = f2bf(v);
      unsigned short lo = f2bf(v - bf2f(h));
      size_t fa = (((size_t)(rr >> 5) * nKBo + (cc >> 4)) * 64 +
                   (rr & 31) + 32 * ((cc >> 3) & 1)) * 8 + (cc & 7);
      Fh[fa] = (short)h; Fl[fa] = (short)lo;
    }
  }
}

// ---- proj GEMM (A = fp32 input x): split-bf16 MFMA, pipelined LDS staging ----
// BM=64, BN=128, 512 thr = 8 waves (2 row x 4 col), per-wave 32x32, BK=32.
template<int ACT, int OUTMODE>
__global__ __launch_bounds__(512) void gemm_mfma(const float* __restrict__ A,
    const short* __restrict__ Bh, const short* __restrict__ Bl,
    const float* __restrict__ bias, float* __restrict__ C,
    ushort_t* __restrict__ C16, short* __restrict__ Fh, short* __restrict__ Fl,
    int N, int M, int K, int nKBo)
{
  __shared__ short Ah[2][2048];
  __shared__ short Al[2][2048];
  const int t = threadIdx.x;
  const int lane = t & 63;
  const int wid = t >> 6;
  const int wr = wid >> 2;
  const int wc = wid & 3;
  const int row0 = blockIdx.x * 64;
  const int col0 = blockIdx.y * 128;
  const int nKB = K >> 4;
  const int nK = K >> 5;

  const int srow = t & 63;
  const int kq = (t >> 6) << 2;
  const int sbase = ((((srow >> 5) * 2 + (kq >> 4)) * 64) +
                     (srow & 31) + 32 * ((kq >> 3) & 1)) * 8 + (kq & 7);
  const bool arow_ok = (row0 + srow) < N;
  const float* aptr = A + (size_t)(row0 + srow) * K + kq;

  const int cb = (col0 >> 5) + wc;
  auto boff = [&](int kb) { return ((size_t)(cb * nKB + kb) * 64 + lane) * 8; };

  f32x16 acc = {};

  float4 aR = make_float4(0, 0, 0, 0);
  if (arow_ok) aR = *(const float4*)aptr;
  bf16x8 bh0 = *(const bf16x8*)&Bh[boff(0)];
  bf16x8 bl0 = *(const bf16x8*)&Bl[boff(0)];
  bf16x8 bh1 = *(const bf16x8*)&Bh[boff(1)];
  bf16x8 bl1 = *(const bf16x8*)&Bl[boff(1)];
  {
    float vin[4] = {aR.x, aR.y, aR.z, aR.w};
    short4v hv, lv;
    #pragma unroll
    for (int q = 0; q < 4; ++q) {
      unsigned short h = f2bf(vin[q]);
      hv[q] = (short)h;
      lv[q] = (short)f2bf(vin[q] - bf2f(h));
    }
    *(short4v*)&Ah[0][sbase] = hv;
    *(short4v*)&Al[0][sbase] = lv;
  }
  __syncthreads();

  for (int ks = 0; ks < nK; ++ks) {
    const int cur = ks & 1;
    const int nxt = cur ^ 1;
    const int ksn = (ks + 1 < nK) ? (ks + 1) : ks;
    float4 aN = make_float4(0, 0, 0, 0);
    if (arow_ok) aN = *(const float4*)(aptr + (size_t)ksn * 32);
    bf16x8 bh0n = *(const bf16x8*)&Bh[boff(ksn * 2)];
    bf16x8 bl0n = *(const bf16x8*)&Bl[boff(ksn * 2)];
    bf16x8 bh1n = *(const bf16x8*)&Bh[boff(ksn * 2 + 1)];
    bf16x8 bl1n = *(const bf16x8*)&Bl[boff(ksn * 2 + 1)];

    bf16x8 a_h0 = *(const bf16x8*)&Ah[cur][((wr * 2 + 0) * 64 + lane) * 8];
    bf16x8 a_l0 = *(const bf16x8*)&Al[cur][((wr * 2 + 0) * 64 + lane) * 8];
    bf16x8 a_h1 = *(const bf16x8*)&Ah[cur][((wr * 2 + 1) * 64 + lane) * 8];
    bf16x8 a_l1 = *(const bf16x8*)&Al[cur][((wr * 2 + 1) * 64 + lane) * 8];
    acc = __builtin_amdgcn_mfma_f32_32x32x16_bf16(a_h0, bh0, acc, 0, 0, 0);
    acc = __builtin_amdgcn_mfma_f32_32x32x16_bf16(a_l0, bh0, acc, 0, 0, 0);
    acc = __builtin_amdgcn_mfma_f32_32x32x16_bf16(a_h0, bl0, acc, 0, 0, 0);
    acc = __builtin_amdgcn_mfma_f32_32x32x16_bf16(a_h1, bh1, acc, 0, 0, 0);
    acc = __builtin_amdgcn_mfma_f32_32x32x16_bf16(a_l1, bh1, acc, 0, 0, 0);
    acc = __builtin_amdgcn_mfma_f32_32x32x16_bf16(a_h1, bl1, acc, 0, 0, 0);

    if (ks + 1 < nK) {
      float vin[4] = {aN.x, aN.y, aN.z, aN.w};
      short4v hv, lv;
      #pragma unroll
      for (int q = 0; q < 4; ++q) {
        unsigned short h = f2bf(vin[q]);
        hv[q] = (short)h;
        lv[q] = (short)f2bf(vin[q] - bf2f(h));
      }
      *(short4v*)&Ah[nxt][sbase] = hv;
      *(short4v*)&Al[nxt][sbase] = lv;
    }
    bh0 = bh0n; bl0 = bl0n; bh1 = bh1n; bl1 = bl1n;
    __syncthreads();
  }

  int cc = col0 + wc * 32 + (lane & 31);
  float bv = (cc < M) ? bias[cc] : 0.f;
  epi_store<ACT, OUTMODE>(acc, row0 + wr * 32, cc, lane, bv, C, C16, Fh, Fl, N, M, nKBo);
}

// ---- frag-direct GEMM: A pre-formed in frag-order bf16 hi/lo (no LDS!) -------
// BM=128, BN=128, 512 thr = 8 waves (4 row x 2 col), per-wave 32r x 64c.
// Pure global-load + MFMA loop; no barriers; latency hidden by TLP/ILP.
template<int ACT, int OUTMODE>
__global__ __launch_bounds__(512) void gemm_fd(
    const short* __restrict__ Ah, const short* __restrict__ Al,
    const short* __restrict__ Bh, const short* __restrict__ Bl,
    const float* __restrict__ bias, float* __restrict__ C,
    ushort_t* __restrict__ C16, short* __restrict__ Fh, short* __restrict__ Fl,
    int N, int M, int nKB, int nKBo)
{
  const int t = threadIdx.x;
  const int lane = t & 63;
  const int wid = t >> 6;
  const int wr = wid >> 1;          // 0..3
  const int wc = wid & 1;           // 0..1
  const int row0 = blockIdx.x * 128;
  const int rowblk = (row0 >> 5) + wr;
  const int cb0 = wc * 2, cb1 = cb0 + 1;

  const short* pAh = Ah + (size_t)rowblk * nKB * 512 + lane * 8;
  const short* pAl = Al + (size_t)rowblk * nKB * 512 + lane * 8;
  const short* pBh0 = Bh + (size_t)cb0 * nKB * 512 + lane * 8;
  const short* pBl0 = Bl + (size_t)cb0 * nKB * 512 + lane * 8;
  const short* pBh1 = Bh + (size_t)cb1 * nKB * 512 + lane * 8;
  const short* pBl1 = Bl + (size_t)cb1 * nKB * 512 + lane * 8;

  f32x16 acc0 = {}, acc1 = {};
  #pragma unroll 2
  for (int kb = 0; kb < nKB; ++kb) {
    size_t o = (size_t)kb * 512;
    bf16x8 ah = *(const bf16x8*)(pAh + o);
    bf16x8 al = *(const bf16x8*)(pAl + o);
    bf16x8 bh0 = *(const bf16x8*)(pBh0 + o);
    bf16x8 bl0 = *(const bf16x8*)(pBl0 + o);
    bf16x8 bh1 = *(const bf16x8*)(pBh1 + o);
    bf16x8 bl1 = *(const bf16x8*)(pBl1 + o);
    acc0 = __builtin_amdgcn_mfma_f32_32x32x16_bf16(ah, bh0, acc0, 0, 0, 0);
    acc0 = __builtin_amdgcn_mfma_f32_32x32x16_bf16(al, bh0, acc0, 0, 0, 0);
    acc0 = __builtin_amdgcn_mfma_f32_32x32x16_bf16(ah, bl0, acc0, 0, 0, 0);
    acc1 = __builtin_amdgcn_mfma_f32_32x32x16_bf16(ah, bh1, acc1, 0, 0, 0);
    acc1 = __builtin_amdgcn_mfma_f32_32x32x16_bf16(al, bh1, acc1, 0, 0, 0);
    acc1 = __builtin_amdgcn_mfma_f32_32x32x16_bf16(ah, bl1, acc1, 0, 0, 0);
  }

  int cc0 = cb0 * 32 + (lane & 31);
  int cc1 = cb1 * 32 + (lane & 31);
  float bv0 = (cc0 < M) ? bias[cc0] : 0.f;
  float bv1 = (cc1 < M) ? bias[cc1] : 0.f;
  epi_store<ACT, OUTMODE>(acc0, row0 + wr * 32, cc0, lane, bv0, C, C16, Fh, Fl, N, M, nKBo);
  epi_store<ACT, OUTMODE>(acc1, row0 + wr * 32, cc1, lane, bv1, C, C16, Fh, Fl, N, M, nKBo);
}

// ---------------- CSR build (dst-sorted edge permutation) ---------------------
__global__ void k_degree(const int* __restrict__ ei, int* __restrict__ deg) {
  int e = blockIdx.x * 256 + threadIdx.x;
  if (e < NE) atomicAdd(&deg[ei[NE + e]], 1);
}

__global__ __launch_bounds__(256) void k_scan1(const int* __restrict__ deg,
    int* __restrict__ rowstart, int* __restrict__ blocksum) {
  __shared__ int sm[256];
  int b = blockIdx.x, t = threadIdx.x;
  int i = b * 256 + t;
  int v = (i < NN) ? deg[i] : 0;
  sm[t] = v;
  __syncthreads();
  #pragma unroll
  for (int off = 1; off < 256; off <<= 1) {
    int u = (t >= off) ? sm[t - off] : 0;
    __syncthreads();
    sm[t] += u;
    __syncthreads();
  }
  if (i < NN) rowstart[i + 1] = sm[t];
  if (t == 255) blocksum[b] = sm[255];
}

__global__ __launch_bounds__(256) void k_scan2(int* __restrict__ blocksum, int nb) {
  __shared__ int sm[256];
  int t = threadIdx.x;
  int v = (t < nb) ? blocksum[t] : 0;
  sm[t] = v;
  __syncthreads();
  #pragma unroll
  for (int off = 1; off < 256; off <<= 1) {
    int u = (t >= off) ? sm[t - off] : 0;
    __syncthreads();
    sm[t] += u;
    __syncthreads();
  }
  if (t < nb) blocksum[t] = (t == 0) ? 0 : sm[t - 1];
}

__global__ __launch_bounds__(256) void k_scan3(int* __restrict__ rowstart,
    const int* __restrict__ blocksum) {
  int b = blockIdx.x, t = threadIdx.x;
  int i = b * 256 + t;
  if (i == 0) rowstart[0] = 0;
  if (i < NN) rowstart[i + 1] += blocksum[b];
}

__global__ void k_scatter(const int* __restrict__ ei, const int* __restrict__ rowstart,
                          int* __restrict__ cursor, int* __restrict__ srcp) {
  int e = blockIdx.x * 256 + threadIdx.x;
  if (e >= NE) return;
  int s = ei[e], d = ei[NE + e];
  int pos = rowstart[d] + atomicAdd(&cursor[d], 1);
  srcp[pos] = s;
}

// -------- fused GATv2 edge+node, channel-packed, 8-edge pipelined -------------
// lane c (0..31) owns channels 4c..4c+3 (head c>>3); butterfly xor 1,2,4.
// Output written in A-frag-order bf16 hi/lo (nKBo=8) for the next GEMM.
__global__ __launch_bounds__(256) void k_gat(const ushort_t* __restrict__ xl,
    const float* __restrict__ xr, const int* __restrict__ srcp,
    const int* __restrict__ rowstart, const float* __restrict__ att,
    const float* __restrict__ bias, short* __restrict__ Fh, short* __restrict__ Fl)
{
  const int g = threadIdx.x >> 5;
  const int c = threadIdx.x & 31;
  const int n = blockIdx.x * 8 + g;
  const int r0 = rowstart[n], r1 = rowstart[n + 1];
  const float4 xrv = *(const float4*)(xr + (size_t)n * 128 + 4 * c);
  const float4 atv = *(const float4*)(att + 4 * c);

  float m = -1e30f, ssum = 0.f;
  float a0 = 0.f, a1 = 0.f, a2 = 0.f, a3 = 0.f;

  auto lg = [&](int s, float4& xs) -> float {
    half4v hv = *(const half4v*)(xl + (size_t)s * 128 + 4 * c);
    xs.x = (float)hv[0]; xs.y = (float)hv[1];
    xs.z = (float)hv[2]; xs.w = (float)hv[3];
    float u0 = xs.x + xrv.x; u0 = fmaxf(u0, 0.2f * u0);
    float u1 = xs.y + xrv.y; u1 = fmaxf(u1, 0.2f * u1);
    float u2 = xs.z + xrv.z; u2 = fmaxf(u2, 0.2f * u2);
    float u3 = xs.w + xrv.w; u3 = fmaxf(u3, 0.2f * u3);
    float l = u0 * atv.x + u1 * atv.y + u2 * atv.z + u3 * atv.w;
    l += __shfl_xor(l, 1);
    l += __shfl_xor(l, 2);
    l += __shfl_xor(l, 4);
    return l;
  };

  int j = r0;
  for (; j + 8 <= r1; j += 8) {
    int s0 = srcp[j],     s1 = srcp[j + 1], s2 = srcp[j + 2], s3 = srcp[j + 3];
    int s4 = srcp[j + 4], s5 = srcp[j + 5], s6 = srcp[j + 6], s7 = srcp[j + 7];
    float4 x0, x1, x2, x3, x4, x5, x6, x7;
    float l0 = lg(s0, x0), l1 = lg(s1, x1), l2 = lg(s2, x2), l3 = lg(s3, x3);
    float l4 = lg(s4, x4), l5 = lg(s5, x5), l6 = lg(s6, x6), l7 = lg(s7, x7);
    float mloc = fmaxf(fmaxf(fmaxf(l0, l1), fmaxf(l2, l3)),
                       fmaxf(fmaxf(l4, l5), fmaxf(l6, l7)));
    float mn = fmaxf(m, mloc);
    float sc = __expf(m - mn);
    float p0 = __expf(l0 - mn), p1 = __expf(l1 - mn);
    float p2 = __expf(l2 - mn), p3 = __expf(l3 - mn);
    float p4 = __expf(l4 - mn), p5 = __expf(l5 - mn);
    float p6 = __expf(l6 - mn), p7 = __expf(l7 - mn);
    ssum = ssum * sc + (((p0 + p1) + (p2 + p3)) + ((p4 + p5) + (p6 + p7)));
    a0 = a0 * sc + (((p0 * x0.x + p1 * x1.x) + (p2 * x2.x + p3 * x3.x)) +
                    ((p4 * x4.x + p5 * x5.x) + (p6 * x6.x + p7 * x7.x)));
    a1 = a1 * sc + (((p0 * x0.y + p1 * x1.y) + (p2 * x2.y + p3 * x3.y)) +
                    ((p4 * x4.y + p5 * x5.y) + (p6 * x6.y + p7 * x7.y)));
    a2 = a2 * sc + (((p0 * x0.z + p1 * x1.z) + (p2 * x2.z + p3 * x3.z)) +
                    ((p4 * x4.z + p5 * x5.z) + (p6 * x6.z + p7 * x7.z)));
    a3 = a3 * sc + (((p0 * x0.w + p1 * x1.w) + (p2 * x2.w + p3 * x3.w)) +
                    ((p4 * x4.w + p5 * x5.w) + (p6 * x6.w + p7 * x7.w)));
    m = mn;
  }
  for (; j + 4 <= r1; j += 4) {
    int s0 = srcp[j], s1 = srcp[j + 1], s2 = srcp[j + 2], s3 = srcp[j + 3];
    float4 x0, x1, x2, x3;
    float l0 = lg(s0, x0), l1 = lg(s1, x1), l2 = lg(s2, x2), l3 = lg(s3, x3);
    float mloc = fmaxf(fmaxf(l0, l1), fmaxf(l2, l3));
    float mn = fmaxf(m, mloc);
    float sc = __expf(m - mn);
    float p0 = __expf(l0 - mn), p1 = __expf(l1 - mn);
    float p2 = __expf(l2 - mn), p3 = __expf(l3 - mn);
    ssum = ssum * sc + ((p0 + p1) + (p2 + p3));
    a0 = a0 * sc + (p0 * x0.x + p1 * x1.x) + (p2 * x2.x + p3 * x3.x);
    a1 = a1 * sc + (p0 * x0.y + p1 * x1.y) + (p2 * x2.y + p3 * x3.y);
    a2 = a2 * sc + (p0 * x0.z + p1 * x1.z) + (p2 * x2.z + p3 * x3.z);
    a3 = a3 * sc + (p0 * x0.w + p1 * x1.w) + (p2 * x2.w + p3 * x3.w);
    m = mn;
  }
  for (; j < r1; ++j) {
    float4 xs;
    float l = lg(srcp[j], xs);
    float mn = fmaxf(m, l);
    float sc = __expf(m - mn);
    float p = __expf(l - mn);
    ssum = ssum * sc + p;
    a0 = a0 * sc + p * xs.x;
    a1 = a1 * sc + p * xs.y;
    a2 = a2 * sc + p * xs.z;
    a3 = a3 * sc + p * xs.w;
    m = mn;
  }

  const float4 bv = *(const float4*)(bias + 4 * c);
  float rinv = 1.f / (ssum + 1e-16f);
  float o0 = a0 * rinv + bv.x;
  float o1 = a1 * rinv + bv.y;
  float o2 = a2 * rinv + bv.z;
  float o3 = a3 * rinv + bv.w;
  o0 = o0 > 0.f ? o0 : (__expf(o0) - 1.f);
  o1 = o1 > 0.f ? o1 : (__expf(o1) - 1.f);
  o2 = o2 > 0.f ? o2 : (__expf(o2) - 1.f);
  o3 = o3 > 0.f ? o3 : (__expf(o3) - 1.f);

  // frag-order hi/lo write: k = 4c..4c+3, kb = c>>2, lane = (n&31)+32*((c>>1)&1)
  float o[4] = {o0, o1, o2, o3};
  short4v hv2, lv2;
  #pragma unroll
  for (int i = 0; i < 4; ++i) {
    unsigned short h = f2bf(o[i]);
    hv2[i] = (short)h;
    lv2[i] = (short)f2bf(o[i] - bf2f(h));
  }
  size_t base = (((size_t)(n >> 5) * 8 + (c >> 2)) * 64 +
                 (n & 31) + 32 * ((c >> 1) & 1)) * 8 + 4 * (c & 1);
  *(short4v*)&Fh[base] = hv2;
  *(short4v*)&Fl[base] = lv2;
}

__global__ void k_report_ws(float* out, int out_size, float wsz) {
  int i = blockIdx.x * 256 + threadIdx.x;
  if (i < out_size) out[i] = (i == 0) ? wsz : 0.f;
}

// -----------------------------------------------------------------------------
extern "C" void kernel_launch(void* const* d_in, const int* in_sizes, int n_in,
                              void* d_out, int out_size, void* d_ws, size_t ws_size,
                              hipStream_t stream)
{
  const float* x    = (const float*)d_in[0];
  const int*   ei   = (const int*)d_in[1];     // int32 [2,E] row-major
  const float* Wp   = (const float*)d_in[2];  const float* bp    = (const float*)d_in[3];
  const float* Wl1  = (const float*)d_in[4];  const float* bl1   = (const float*)d_in[5];
  const float* Wr1  = (const float*)d_in[6];  const float* br1   = (const float*)d_in[7];
  const float* att1 = (const float*)d_in[8];  const float* bias1 = (const float*)d_in[9];
  const float* Wl2  = (const float*)d_in[10]; const float* bl2   = (const float*)d_in[11];
  const float* Wr2  = (const float*)d_in[12]; const float* br2   = (const float*)d_in[13];
  const float* att2 = (const float*)d_in[14]; const float* bias2 = (const float*)d_in[15];
  const float* W1   = (const float*)d_in[16]; const float* b1    = (const float*)d_in[17];
  const float* W2   = (const float*)d_in[18]; const float* b2    = (const float*)d_in[19];
  float* out = (float*)d_out;

  constexpr size_t NEED = 122300000;
  if (ws_size < NEED) {
    k_report_ws<<<(out_size + 255) / 256, 256, 0, stream>>>(out, out_size, (float)ws_size);
    return;
  }
  char* ws = (char*)d_ws;
  // frag region (sequential reuse): h0f -> h1f -> h2f -> h3f
  short*    h0fh = (short*)(ws + 0);            // 25,624,576 B (1564*16*512*2)
  short*    h0fl = (short*)(ws + 25624576);
  short*    h1fh = (short*)(ws + 0);            // 12,812,288 B (overwrites dead h0f)
  short*    h1fl = (short*)(ws + 12812288);
  short*    h2fh = (short*)(ws + 25624576);
  short*    h2fl = (short*)(ws + 38436864);     // ends 51,249,152
  short*    h3fh = (short*)(ws + 0);            // 3,203,072 B (overwrites dead h1f)
  short*    h3fl = (short*)(ws + 3203072);
  float*    xr   = (float*)(ws + 51300000);     // 25.6 MB
  ushort_t* xlh  = (ushort_t*)(ws + 76900000);  // 12.8 MB
  short*    wb   = (short*)(ws + 89700000);     // weight frag buffers ~1 MB
  int*      srcp = (int*)(ws + 90700000);       // 3.2 MB
  int*      deg  = (int*)(ws + 93900000);
  int*      curs = (int*)(ws + 94100000);
  int*      rowst= (int*)(ws + 94300000);
  int*      bsum = (int*)(ws + 94600000);

  short* Wph  = wb;            short* Wpl  = wb + 131072;
  short* Wl1h = wb + 262144;   short* Wl1l = wb + 294912;
  short* Wr1h = wb + 327680;   short* Wr1l = wb + 360448;
  short* Wl2h = wb + 393216;   short* Wl2l = wb + 409600;
  short* Wr2h = wb + 425984;   short* Wr2l = wb + 442368;
  short* W1h  = wb + 458752;   short* W1l  = wb + 475136;
  short* W2h  = wb + 491520;   short* W2l  = wb + 495616;

  hipMemsetAsync(deg,  0, NN*sizeof(int), stream);
  hipMemsetAsync(curs, 0, NN*sizeof(int), stream);

  k_wconv<<<(131072+255)/256, 256, 0, stream>>>(Wp,  Wph,  Wpl,  256, 512, 131072);
  k_wconv<<<(32768+255)/256,  256, 0, stream>>>(Wl1, Wl1h, Wl1l, 128, 256, 32768);
  k_wconv<<<(32768+255)/256,  256, 0, stream>>>(Wr1, Wr1h, Wr1l, 128, 256, 32768);
  k_wconv<<<(16384+255)/256,  256, 0, stream>>>(Wl2, Wl2h, Wl2l, 128, 128, 16384);
  k_wconv<<<(16384+255)/256,  256, 0, stream>>>(Wr2, Wr2h, Wr2l, 128, 128, 16384);
  k_wconv<<<(16384+255)/256,  256, 0, stream>>>(W1,  W1h,  W1l,  32,  128, 16384);
  k_wconv<<<(4096+255)/256,   256, 0, stream>>>(W2,  W2h,  W2l,  10,  32,  4096);

  constexpr int NB = (NN + 255) / 256;
  k_degree <<<(NE+255)/256, 256, 0, stream>>>(ei, deg);
  k_scan1  <<<NB, 256, 0, stream>>>(deg, rowst, bsum);
  k_scan2  <<<1, 256, 0, stream>>>(bsum, NB);
  k_scan3  <<<NB, 256, 0, stream>>>(rowst, bsum);
  k_scatter<<<(NE+255)/256, 256, 0, stream>>>(ei, rowst, curs, srcp);

  constexpr int GX64  = (NN + 63) / 64;    // 782
  constexpr int GX128 = (NN + 127) / 128;  // 391

  // projection: h0f = elu(x @ Wp^T + bp) in frag order (M=256, K=512, nKBo=16)
  gemm_mfma<1,2><<<dim3(GX64, 2), 512, 0, stream>>>(
      x, Wph, Wpl, bp, nullptr, nullptr, h0fh, h0fl, NN, 256, 512, 16);

  // GAT layer 1 (A = h0f, nKB=16)
  gemm_fd<0,1><<<GX128, 512, 0, stream>>>(h0fh, h0fl, Wl1h, Wl1l, bl1,
      nullptr, xlh, nullptr, nullptr, NN, 128, 16, 0);
  gemm_fd<0,0><<<GX128, 512, 0, stream>>>(h0fh, h0fl, Wr1h, Wr1l, br1,
      xr, nullptr, nullptr, nullptr, NN, 128, 16, 0);
  k_gat<<<NN/8, 256, 0, stream>>>(xlh, xr, srcp, rowst, att1, bias1, h1fh, h1fl);

  // GAT layer 2 (A = h1f, nKB=8)
  gemm_fd<0,1><<<GX128, 512, 0, stream>>>(h1fh, h1fl, Wl2h, Wl2l, bl2,
      nullptr, xlh, nullptr, nullptr, NN, 128, 8, 0);
  gemm_fd<0,0><<<GX128, 512, 0, stream>>>(h1fh, h1fl, Wr2h, Wr2l, br2,
      xr, nullptr, nullptr, nullptr, NN, 128, 8, 0);
  k_gat<<<NN/8, 256, 0, stream>>>(xlh, xr, srcp, rowst, att2, bias2, h2fh, h2fl);

  // head MLP: h3f = elu(h2 @ W1^T + b1) frag (M=32, nKBo=2); out = h3 @ W2^T + b2
  gemm_fd<1,2><<<GX128, 512, 0, stream>>>(h2fh, h2fl, W1h, W1l, b1,
      nullptr, nullptr, h3fh, h3fl, NN, 32, 8, 2);
  gemm_fd<0,0><<<GX128, 512, 0, stream>>>(h3fh, h3fl, W2h, W2l, b2,
      out, nullptr, nullptr, nullptr, NN, 10, 2, 0);
}

// Round 9
// 389.473 us; speedup vs baseline: 1.0483x; 1.0483x over previous
//
#include <hip/hip_runtime.h>
#include <cstdint>
#include <cstddef>

constexpr int NN = 50000;
constexpr int NE = 800000;

typedef short bf16x8 __attribute__((ext_vector_type(8)));
typedef short short4v __attribute__((ext_vector_type(4)));
typedef float f32x16 __attribute__((ext_vector_type(16)));
typedef _Float16 half4v __attribute__((ext_vector_type(4)));
typedef unsigned short ushort_t;

__device__ inline unsigned short f2bf(float f) {
  unsigned u = __float_as_uint(f);
  return (unsigned short)((u + 0x7FFFu + ((u >> 16) & 1u)) >> 16);
}
__device__ inline float bf2f(unsigned short h) {
  return __uint_as_float(((unsigned)h) << 16);
}
__device__ inline ushort_t f2h(float f) {
  _Float16 h = (_Float16)f;
  return __builtin_bit_cast(ushort_t, h);
}

// ---- pre-transform weights W[M][K] fp32 -> frag-order bf16 hi/lo -------------
// idx = ((cb*(K/16)+kb)*64 + l)*8 + j ; col = cb*32+(l&31); k = kb*16+((l>>5)&1)*8+j
__global__ void k_wconv(const float* __restrict__ W, short* __restrict__ Bh,
                        short* __restrict__ Bl, int M, int K, int total) {
  int idx = blockIdx.x * 256 + threadIdx.x;
  if (idx >= total) return;
  int j = idx & 7;
  int l = (idx >> 3) & 63;
  int blk = idx >> 9;
  int nKB = K >> 4;
  int cb = blk / nKB, kb = blk - cb * nKB;
  int col = cb * 32 + (l & 31);
  int k = kb * 16 + ((l >> 5) & 1) * 8 + j;
  float v = (col < M) ? W[(size_t)col * K + k] : 0.f;
  unsigned short h = f2bf(v);
  Bh[idx] = (short)h;
  Bl[idx] = (short)f2bf(v - bf2f(h));
}

// ---- split-bf16 MFMA GEMM, software-pipelined, templated K-step --------------
// BM=64, BN=128, 512 thr = 8 waves (2 row x 4 col), per-wave 32x32, BK=BKT.
// Double-buffered LDS A-tile (hi/lo, fragment order). B frag-order in global
// (L2-hot), loaded in-phase (unrolled so loads hoist). A-prefetch one step
// ahead; one barrier per K-step. BKT=64: 12 MFMA/barrier.
template<int ACT, int H16, int BKT>
__global__ __launch_bounds__(512) void gemm_mfma(const float* __restrict__ A,
    const short* __restrict__ Bh, const short* __restrict__ Bl,
    const float* __restrict__ bias, float* __restrict__ C,
    ushort_t* __restrict__ C16, int N, int M, int K)
{
  constexpr int NKK = BKT / 16;     // 16-k blocks per step (2 or 4)
  constexpr int EPT = BKT / 8;      // k-elems per staging thread (4 or 8)
  __shared__ short Ah[2][2 * NKK * 512];
  __shared__ short Al[2][2 * NKK * 512];
  const int t = threadIdx.x;
  const int lane = t & 63;
  const int wid = t >> 6;
  const int wr = wid >> 2;           // 0..1 row-tile
  const int wc = wid & 3;            // 0..3 col-tile
  const int row0 = blockIdx.x * 64;
  const int col0 = blockIdx.y * 128;
  const int nKB = K >> 4;
  const int nK = K / BKT;

  // staging: thread handles EPT consecutive k of one row
  const int srow = t & 63;
  const int kq = (t >> 6) * EPT;     // multiple of EPT
  const int sbase = ((srow >> 5) * NKK + (kq >> 4)) * 512 +
                    ((srow & 31) + 32 * ((kq >> 3) & 1)) * 8 + (kq & 7);
  const bool arow_ok = (row0 + srow) < N;
  const float* aptr = A + (size_t)(row0 + srow) * K + kq;

  const int cb = (col0 >> 5) + wc;

  f32x16 acc = {};

  float vin[EPT];
  auto aload = [&](int ks) {
    #pragma unroll
    for (int q = 0; q < EPT; ++q) vin[q] = 0.f;
    if (arow_ok) {
      #pragma unroll
      for (int q4 = 0; q4 < EPT / 4; ++q4) {
        float4 v = *(const float4*)(aptr + (size_t)ks * BKT + q4 * 4);
        vin[q4 * 4 + 0] = v.x; vin[q4 * 4 + 1] = v.y;
        vin[q4 * 4 + 2] = v.z; vin[q4 * 4 + 3] = v.w;
      }
    }
  };
  auto stage_write = [&](int buf) {
    if constexpr (EPT == 8) {
      bf16x8 hv, lv;
      #pragma unroll
      for (int q = 0; q < 8; ++q) {
        unsigned short h = f2bf(vin[q]);
        hv[q] = (short)h;
        lv[q] = (short)f2bf(vin[q] - bf2f(h));
      }
      *(bf16x8*)&Ah[buf][sbase] = hv;
      *(bf16x8*)&Al[buf][sbase] = lv;
    } else {
      short4v hv, lv;
      #pragma unroll
      for (int q = 0; q < 4; ++q) {
        unsigned short h = f2bf(vin[q]);
        hv[q] = (short)h;
        lv[q] = (short)f2bf(vin[q] - bf2f(h));
      }
      *(short4v*)&Ah[buf][sbase] = hv;
      *(short4v*)&Al[buf][sbase] = lv;
    }
  };

  // prologue: stage step 0
  aload(0);
  stage_write(0);
  __syncthreads();

  for (int ks = 0; ks < nK; ++ks) {
    const int cur = ks & 1;
    const int nxt = cur ^ 1;
    const bool have_next = (ks + 1 < nK);
    if (have_next) aload(ks + 1);   // issue next-step A loads before MFMA phase

    #pragma unroll
    for (int kk = 0; kk < NKK; ++kk) {
      const int kbg = ks * NKK + kk;
      const size_t bo = ((size_t)(cb * nKB + kbg) * 64 + lane) * 8;
      bf16x8 bh = *(const bf16x8*)&Bh[bo];
      bf16x8 bl = *(const bf16x8*)&Bl[bo];
      bf16x8 ah = *(const bf16x8*)&Ah[cur][(wr * NKK + kk) * 512 + lane * 8];
      bf16x8 al = *(const bf16x8*)&Al[cur][(wr * NKK + kk) * 512 + lane * 8];
      acc = __builtin_amdgcn_mfma_f32_32x32x16_bf16(ah, bh, acc, 0, 0, 0);
      acc = __builtin_amdgcn_mfma_f32_32x32x16_bf16(al, bh, acc, 0, 0, 0);
      acc = __builtin_amdgcn_mfma_f32_32x32x16_bf16(ah, bl, acc, 0, 0, 0);
    }

    if (have_next) stage_write(nxt);
    __syncthreads();
  }

  // epilogue: D layout col=lane&31, row=(reg&3)+8*(reg>>2)+4*(lane>>5)
  int cc = col0 + wc * 32 + (lane & 31);
  float bv = (cc < M) ? bias[cc] : 0.f;
  #pragma unroll
  for (int r = 0; r < 16; ++r) {
    int rr = row0 + wr * 32 + (r & 3) + 8 * (r >> 2) + 4 * (lane >> 5);
    if (rr < N && cc < M) {
      float v = acc[r] + bv;
      if (ACT) v = v > 0.f ? v : (__expf(v) - 1.f);
      if (H16) C16[(size_t)rr * M + cc] = f2h(v);
      else     C[(size_t)rr * M + cc] = v;
    }
  }
}

// ---------------- CSR build (dst-sorted edge permutation) ---------------------
__global__ void k_degree(const int* __restrict__ ei, int* __restrict__ deg) {
  int e = blockIdx.x * 256 + threadIdx.x;
  if (e < NE) atomicAdd(&deg[ei[NE + e]], 1);
}

__global__ __launch_bounds__(256) void k_scan1(const int* __restrict__ deg,
    int* __restrict__ rowstart, int* __restrict__ blocksum) {
  __shared__ int sm[256];
  int b = blockIdx.x, t = threadIdx.x;
  int i = b * 256 + t;
  int v = (i < NN) ? deg[i] : 0;
  sm[t] = v;
  __syncthreads();
  #pragma unroll
  for (int off = 1; off < 256; off <<= 1) {
    int u = (t >= off) ? sm[t - off] : 0;
    __syncthreads();
    sm[t] += u;
    __syncthreads();
  }
  if (i < NN) rowstart[i + 1] = sm[t];
  if (t == 255) blocksum[b] = sm[255];
}

__global__ __launch_bounds__(256) void k_scan2(int* __restrict__ blocksum, int nb) {
  __shared__ int sm[256];
  int t = threadIdx.x;
  int v = (t < nb) ? blocksum[t] : 0;
  sm[t] = v;
  __syncthreads();
  #pragma unroll
  for (int off = 1; off < 256; off <<= 1) {
    int u = (t >= off) ? sm[t - off] : 0;
    __syncthreads();
    sm[t] += u;
    __syncthreads();
  }
  if (t < nb) blocksum[t] = (t == 0) ? 0 : sm[t - 1];
}

__global__ __launch_bounds__(256) void k_scan3(int* __restrict__ rowstart,
    const int* __restrict__ blocksum) {
  int b = blockIdx.x, t = threadIdx.x;
  int i = b * 256 + t;
  if (i == 0) rowstart[0] = 0;
  if (i < NN) rowstart[i + 1] += blocksum[b];
}

__global__ void k_scatter(const int* __restrict__ ei, const int* __restrict__ rowstart,
                          int* __restrict__ cursor, int* __restrict__ srcp) {
  int e = blockIdx.x * 256 + threadIdx.x;
  if (e >= NE) return;
  int s = ei[e], d = ei[NE + e];
  int pos = rowstart[d] + atomicAdd(&cursor[d], 1);
  srcp[pos] = s;
}

// -------- fused GATv2 edge+node, channel-packed, 8-edge pipelined -------------
// lane c (0..31) owns channels 4c..4c+3 (head c>>3); butterfly xor 1,2,4.
// Block = 256 thr = 8 nodes. Coalesced float4 output.
__global__ __launch_bounds__(256) void k_gat(const ushort_t* __restrict__ xl,
    const float* __restrict__ xr, const int* __restrict__ srcp,
    const int* __restrict__ rowstart, const float* __restrict__ att,
    const float* __restrict__ bias, float* __restrict__ out)
{
  const int g = threadIdx.x >> 5;
  const int c = threadIdx.x & 31;
  const int n = blockIdx.x * 8 + g;
  const int r0 = rowstart[n], r1 = rowstart[n + 1];
  const float4 xrv = *(const float4*)(xr + (size_t)n * 128 + 4 * c);
  const float4 atv = *(const float4*)(att + 4 * c);

  float m = -1e30f, ssum = 0.f;
  float a0 = 0.f, a1 = 0.f, a2 = 0.f, a3 = 0.f;

  auto lg = [&](int s, float4& xs) -> float {
    half4v hv = *(const half4v*)(xl + (size_t)s * 128 + 4 * c);
    xs.x = (float)hv[0]; xs.y = (float)hv[1];
    xs.z = (float)hv[2]; xs.w = (float)hv[3];
    float u0 = xs.x + xrv.x; u0 = fmaxf(u0, 0.2f * u0);
    float u1 = xs.y + xrv.y; u1 = fmaxf(u1, 0.2f * u1);
    float u2 = xs.z + xrv.z; u2 = fmaxf(u2, 0.2f * u2);
    float u3 = xs.w + xrv.w; u3 = fmaxf(u3, 0.2f * u3);
    float l = u0 * atv.x + u1 * atv.y + u2 * atv.z + u3 * atv.w;
    l += __shfl_xor(l, 1);
    l += __shfl_xor(l, 2);
    l += __shfl_xor(l, 4);
    return l;
  };

  int j = r0;
  for (; j + 8 <= r1; j += 8) {
    int s0 = srcp[j],     s1 = srcp[j + 1], s2 = srcp[j + 2], s3 = srcp[j + 3];
    int s4 = srcp[j + 4], s5 = srcp[j + 5], s6 = srcp[j + 6], s7 = srcp[j + 7];
    float4 x0, x1, x2, x3, x4, x5, x6, x7;
    float l0 = lg(s0, x0), l1 = lg(s1, x1), l2 = lg(s2, x2), l3 = lg(s3, x3);
    float l4 = lg(s4, x4), l5 = lg(s5, x5), l6 = lg(s6, x6), l7 = lg(s7, x7);
    float mloc = fmaxf(fmaxf(fmaxf(l0, l1), fmaxf(l2, l3)),
                       fmaxf(fmaxf(l4, l5), fmaxf(l6, l7)));
    float mn = fmaxf(m, mloc);
    float sc = __expf(m - mn);
    float p0 = __expf(l0 - mn), p1 = __expf(l1 - mn);
    float p2 = __expf(l2 - mn), p3 = __expf(l3 - mn);
    float p4 = __expf(l4 - mn), p5 = __expf(l5 - mn);
    float p6 = __expf(l6 - mn), p7 = __expf(l7 - mn);
    ssum = ssum * sc + (((p0 + p1) + (p2 + p3)) + ((p4 + p5) + (p6 + p7)));
    a0 = a0 * sc + (((p0 * x0.x + p1 * x1.x) + (p2 * x2.x + p3 * x3.x)) +
                    ((p4 * x4.x + p5 * x5.x) + (p6 * x6.x + p7 * x7.x)));
    a1 = a1 * sc + (((p0 * x0.y + p1 * x1.y) + (p2 * x2.y + p3 * x3.y)) +
                    ((p4 * x4.y + p5 * x5.y) + (p6 * x6.y + p7 * x7.y)));
    a2 = a2 * sc + (((p0 * x0.z + p1 * x1.z) + (p2 * x2.z + p3 * x3.z)) +
                    ((p4 * x4.z + p5 * x5.z) + (p6 * x6.z + p7 * x7.z)));
    a3 = a3 * sc + (((p0 * x0.w + p1 * x1.w) + (p2 * x2.w + p3 * x3.w)) +
                    ((p4 * x4.w + p5 * x5.w) + (p6 * x6.w + p7 * x7.w)));
    m = mn;
  }
  for (; j + 4 <= r1; j += 4) {
    int s0 = srcp[j], s1 = srcp[j + 1], s2 = srcp[j + 2], s3 = srcp[j + 3];
    float4 x0, x1, x2, x3;
    float l0 = lg(s0, x0), l1 = lg(s1, x1), l2 = lg(s2, x2), l3 = lg(s3, x3);
    float mloc = fmaxf(fmaxf(l0, l1), fmaxf(l2, l3));
    float mn = fmaxf(m, mloc);
    float sc = __expf(m - mn);
    float p0 = __expf(l0 - mn), p1 = __expf(l1 - mn);
    float p2 = __expf(l2 - mn), p3 = __expf(l3 - mn);
    ssum = ssum * sc + ((p0 + p1) + (p2 + p3));
    a0 = a0 * sc + (p0 * x0.x + p1 * x1.x) + (p2 * x2.x + p3 * x3.x);
    a1 = a1 * sc + (p0 * x0.y + p1 * x1.y) + (p2 * x2.y + p3 * x3.y);
    a2 = a2 * sc + (p0 * x0.z + p1 * x1.z) + (p2 * x2.z + p3 * x3.z);
    a3 = a3 * sc + (p0 * x0.w + p1 * x1.w) + (p2 * x2.w + p3 * x3.w);
    m = mn;
  }
  for (; j < r1; ++j) {
    float4 xs;
    float l = lg(srcp[j], xs);
    float mn = fmaxf(m, l);
    float sc = __expf(m - mn);
    float p = __expf(l - mn);
    ssum = ssum * sc + p;
    a0 = a0 * sc + p * xs.x;
    a1 = a1 * sc + p * xs.y;
    a2 = a2 * sc + p * xs.z;
    a3 = a3 * sc + p * xs.w;
    m = mn;
  }

  const float4 bv = *(const float4*)(bias + 4 * c);
  float rinv = 1.f / (ssum + 1e-16f);
  float o0 = a0 * rinv + bv.x;
  float o1 = a1 * rinv + bv.y;
  float o2 = a2 * rinv + bv.z;
  float o3 = a3 * rinv + bv.w;
  o0 = o0 > 0.f ? o0 : (__expf(o0) - 1.f);
  o1 = o1 > 0.f ? o1 : (__expf(o1) - 1.f);
  o2 = o2 > 0.f ? o2 : (__expf(o2) - 1.f);
  o3 = o3 > 0.f ? o3 : (__expf(o3) - 1.f);
  *(float4*)(out + (size_t)n * 128 + 4 * c) = make_float4(o0, o1, o2, o3);
}

__global__ void k_report_ws(float* out, int out_size, float wsz) {
  int i = blockIdx.x * 256 + threadIdx.x;
  if (i < out_size) out[i] = (i == 0) ? wsz : 0.f;
}

// -----------------------------------------------------------------------------
extern "C" void kernel_launch(void* const* d_in, const int* in_sizes, int n_in,
                              void* d_out, int out_size, void* d_ws, size_t ws_size,
                              hipStream_t stream)
{
  const float* x    = (const float*)d_in[0];
  const int*   ei   = (const int*)d_in[1];     // int32 [2,E] row-major
  const float* Wp   = (const float*)d_in[2];  const float* bp    = (const float*)d_in[3];
  const float* Wl1  = (const float*)d_in[4];  const float* bl1   = (const float*)d_in[5];
  const float* Wr1  = (const float*)d_in[6];  const float* br1   = (const float*)d_in[7];
  const float* att1 = (const float*)d_in[8];  const float* bias1 = (const float*)d_in[9];
  const float* Wl2  = (const float*)d_in[10]; const float* bl2   = (const float*)d_in[11];
  const float* Wr2  = (const float*)d_in[12]; const float* br2   = (const float*)d_in[13];
  const float* att2 = (const float*)d_in[14]; const float* bias2 = (const float*)d_in[15];
  const float* W1   = (const float*)d_in[16]; const float* b1    = (const float*)d_in[17];
  const float* W2   = (const float*)d_in[18]; const float* b2    = (const float*)d_in[19];
  float* out = (float*)d_out;

  constexpr size_t NEED = 122300000;
  if (ws_size < NEED) {
    k_report_ws<<<(out_size + 255) / 256, 256, 0, stream>>>(out, out_size, (float)ws_size);
    return;
  }
  char* ws = (char*)d_ws;
  float*    h0    = (float*)(ws + 0);             // 50000*256 f32
  float*    h1    = h0;                           // reuse
  float*    h2    = (float*)(ws + 25600000);
  ushort_t* xlh   = (ushort_t*)(ws + 51200000);   // fp16 mirror, 12.8 MB
  float*    xr    = (float*)(ws + 76800000);
  float*    h3    = (float*)(ws + 102400000);     // 50000*32
  short*    wb    = (short*)(ws + 108800000);     // weight hi/lo frag buffers (<1MB)
  int*      srcp  = (int*)(ws + 115200000);
  int*      deg   = (int*)(ws + 121600000);
  int*      curs  = (int*)(ws + 121800000);
  int*      rowst = (int*)(ws + 122000000);
  int*      bsum  = (int*)(ws + 122250000);

  short* Wph  = wb;            short* Wpl  = wb + 131072;
  short* Wl1h = wb + 262144;   short* Wl1l = wb + 294912;
  short* Wr1h = wb + 327680;   short* Wr1l = wb + 360448;
  short* Wl2h = wb + 393216;   short* Wl2l = wb + 409600;
  short* Wr2h = wb + 425984;   short* Wr2l = wb + 442368;
  short* W1h  = wb + 458752;   short* W1l  = wb + 475136;
  short* W2h  = wb + 491520;   short* W2l  = wb + 495616;

  hipMemsetAsync(deg,  0, NN*sizeof(int), stream);
  hipMemsetAsync(curs, 0, NN*sizeof(int), stream);

  k_wconv<<<(131072+255)/256, 256, 0, stream>>>(Wp,  Wph,  Wpl,  256, 512, 131072);
  k_wconv<<<(32768+255)/256,  256, 0, stream>>>(Wl1, Wl1h, Wl1l, 128, 256, 32768);
  k_wconv<<<(32768+255)/256,  256, 0, stream>>>(Wr1, Wr1h, Wr1l, 128, 256, 32768);
  k_wconv<<<(16384+255)/256,  256, 0, stream>>>(Wl2, Wl2h, Wl2l, 128, 128, 16384);
  k_wconv<<<(16384+255)/256,  256, 0, stream>>>(Wr2, Wr2h, Wr2l, 128, 128, 16384);
  k_wconv<<<(16384+255)/256,  256, 0, stream>>>(W1,  W1h,  W1l,  32,  128, 16384);
  k_wconv<<<(4096+255)/256,   256, 0, stream>>>(W2,  W2h,  W2l,  10,  32,  4096);

  constexpr int NB = (NN + 255) / 256;
  k_degree <<<(NE+255)/256, 256, 0, stream>>>(ei, deg);
  k_scan1  <<<NB, 256, 0, stream>>>(deg, rowst, bsum);
  k_scan2  <<<1, 256, 0, stream>>>(bsum, NB);
  k_scan3  <<<NB, 256, 0, stream>>>(rowst, bsum);
  k_scatter<<<(NE+255)/256, 256, 0, stream>>>(ei, rowst, curs, srcp);

  constexpr int GX = (NN + 63) / 64;  // 782

  // projection: h0 = elu(x @ Wp^T + bp), M=256, K=512
  gemm_mfma<1,0,64><<<dim3(GX, 2), 512, 0, stream>>>(x, Wph, Wpl, bp, h0, nullptr, NN, 256, 512);

  // GAT layer 1
  gemm_mfma<0,1,64><<<dim3(GX, 1), 512, 0, stream>>>(h0, Wl1h, Wl1l, bl1, nullptr, xlh, NN, 128, 256);
  gemm_mfma<0,0,64><<<dim3(GX, 1), 512, 0, stream>>>(h0, Wr1h, Wr1l, br1, xr, nullptr, NN, 128, 256);
  k_gat<<<NN/8, 256, 0, stream>>>(xlh, xr, srcp, rowst, att1, bias1, h1);

  // GAT layer 2
  gemm_mfma<0,1,64><<<dim3(GX, 1), 512, 0, stream>>>(h1, Wl2h, Wl2l, bl2, nullptr, xlh, NN, 128, 128);
  gemm_mfma<0,0,64><<<dim3(GX, 1), 512, 0, stream>>>(h1, Wr2h, Wr2l, br2, xr, nullptr, NN, 128, 128);
  k_gat<<<NN/8, 256, 0, stream>>>(xlh, xr, srcp, rowst, att2, bias2, h2);

  // head MLP
  gemm_mfma<1,0,64><<<dim3(GX, 1), 512, 0, stream>>>(h2, W1h, W1l, b1, h3, nullptr, NN, 32, 128);
  gemm_mfma<0,0,32><<<dim3(GX, 1), 512, 0, stream>>>(h3, W2h, W2l, b2, out, nullptr, NN, 10, 32);
}